// Round 3
// baseline (150.228 us; speedup 1.0000x reference)
//
#include <hip/hip_runtime.h>
#include <math.h>

#define SDIM 4096
#define DIN  1024
#define DOUT 64
#define BB   4
#define MTOT (BB * SDIM)   // 16384 rows
#define SMAX 12.0f         // fixed softmax max (log2 domain); true max ~8

typedef __attribute__((ext_vector_type(8))) short short8;    // 8 x bf16
typedef __attribute__((ext_vector_type(4))) float floatx4;
typedef __attribute__((ext_vector_type(16))) float floatx16;

static __device__ __forceinline__ unsigned short f2bf(float f) {
  union { float f; unsigned int u; } v; v.f = f;
  unsigned int r = v.u + 0x7fffu + ((v.u >> 16) & 1u);
  return (unsigned short)(r >> 16);
}

static __device__ __forceinline__ floatx4 mfma16(short8 a, short8 b, floatx4 c) {
  return __builtin_amdgcn_mfma_f32_16x16x32_bf16(a, b, c, 0, 0, 0);
}
static __device__ __forceinline__ floatx16 mfma32(short8 a, short8 b, floatx16 c) {
  return __builtin_amdgcn_mfma_f32_32x32x16_bf16(a, b, c, 0, 0, 0);
}
// pack two f32 -> one dword of 2 bf16 (lo = src0)
static __device__ __forceinline__ unsigned int cvtpk(float lo, float hi) {
  unsigned int r;
  asm("v_cvt_pk_bf16_f32 %0, %1, %2" : "=v"(r) : "v"(lo), "v"(hi));
  return r;
}

// ---------------------------------------------------------------------------
// W -> bf16:  wb[o][k].  q scale folds 1/sqrt(64) AND log2(e) (exp2 domain).
// ---------------------------------------------------------------------------
__global__ __launch_bounds__(256) void wcvt_kernel(
    const float* __restrict__ Wq, const float* __restrict__ Wk,
    const float* __restrict__ Wv, unsigned short* __restrict__ wb) {
  const int idx  = blockIdx.x * 256 + threadIdx.x;
  const int flat = idx * 4;
  const int m    = flat >> 16;
  const int off  = flat & 65535;
  const float* src = (m == 0) ? Wq : (m == 1) ? Wk : Wv;
  const float  s   = (m == 0) ? 0.125f * 1.44269504f : 1.0f;
  float4 v = *(const float4*)(src + off);
  ushort4 u;
  u.x = f2bf(v.x * s); u.y = f2bf(v.y * s);
  u.z = f2bf(v.z * s); u.w = f2bf(v.w * s);
  *(ushort4*)(wb + (size_t)m * 65536 + off) = u;
}

// ---------------------------------------------------------------------------
// Projection: out = x(16384x1024) @ wb^T(1024x192). Main loop unchanged
// (proven). Epilogue stages through LDS and emits FRAGMENT-MAJOR layouts so
// attn_kernel's every load is one coalesced 64-lane x 16B dwordx4:
//   Q/K frag: buf[(b*128+blk)*2048 + s*512 + lane*8 + j]
//             = elem(row = blk*32 + (lane&31), d = s*16 + (lane>>5)*8 + j)
//   V   frag: buf[(b*64+kt)*4096 + dh*2048 + s*512 + lane*8 + j]
//             = V(key = kt*64 + s*16 + (lane>>5)*8 + j, d = dh*32 + (lane&31))
// ---------------------------------------------------------------------------
__global__ __launch_bounds__(256) void proj_kernel(
    const float* __restrict__ x, const unsigned short* __restrict__ wb,
    unsigned short* __restrict__ qfb, unsigned short* __restrict__ kfb,
    unsigned short* __restrict__ vfb) {
  __shared__ __align__(16) short Xs[32][136];   // 32 x 128 bf16 (also epi Q/K)
  __shared__ __align__(16) short Vl[64][40];    // V^T tile [d][seq_local]

  const int tid  = threadIdx.x;
  const int wave = tid >> 6;
  const int lane = tid & 63;
  const int quad = lane >> 4;
  const int l16  = lane & 15;
  const int l32  = lane & 31;
  const int hl   = lane >> 5;
  const int row0 = blockIdx.x * 32;

  floatx4 acc[2][3];
#pragma unroll
  for (int i = 0; i < 2; i++)
#pragma unroll
    for (int j = 0; j < 3; j++) acc[i][j] = floatx4{0, 0, 0, 0};

  const int sr = tid >> 3;          // staging row 0..31
  const int sc = (tid & 7) * 16;    // staging col (floats) {0,16,...,112}

  float4 xa[4];
  {
    const float* xp = x + (size_t)(row0 + sr) * DIN + sc;
#pragma unroll
    for (int i = 0; i < 4; i++) xa[i] = *(const float4*)(xp + i * 4);
  }

  for (int k0 = 0; k0 < DIN; k0 += 128) {
    __syncthreads();
    short8 s0, s1;
#pragma unroll
    for (int i = 0; i < 4; i++) {
      s0[i]     = f2bf(xa[0][i]); s0[i + 4] = f2bf(xa[1][i]);
      s1[i]     = f2bf(xa[2][i]); s1[i + 4] = f2bf(xa[3][i]);
    }
    *(short8*)&Xs[sr][sc]     = s0;
    *(short8*)&Xs[sr][sc + 8] = s1;
    __syncthreads();

    if (k0 + 128 < DIN) {
      const float* xp = x + (size_t)(row0 + sr) * DIN + (k0 + 128) + sc;
#pragma unroll
      for (int i = 0; i < 4; i++) xa[i] = *(const float4*)(xp + i * 4);
    }

#pragma unroll
    for (int s = 0; s < 4; s++) {   // 4 k-steps of 32
      const short8 a0 = *(const short8*)&Xs[l16][s * 32 + quad * 8];
      const short8 a1 = *(const short8*)&Xs[16 + l16][s * 32 + quad * 8];
#pragma unroll
      for (int f = 0; f < 3; f++) {
        const int col = (wave * 3 + f) * 16 + l16;
        const short8 b =
            *(const short8*)(wb + (size_t)col * DIN + k0 + s * 32 + quad * 8);
        acc[0][f] = mfma16(a0, b, acc[0][f]);
        acc[1][f] = mfma16(a1, b, acc[1][f]);
      }
    }
  }

  // ---- epilogue: LDS re-layout -> fragment-major coalesced stores ----
  const int b4   = row0 >> 12;       // batch
  const int seq  = row0 & 4095;      // seq offset within batch
  const int qw   = seq >> 5;         // 32-row block index 0..127
  const int kt   = seq >> 6;         // 64-key tile index 0..63
  const int hsel = (seq >> 5) & 1;   // which half of the 64-key tile

  __syncthreads();                   // Xs free for reuse

  // phase A: scatter Q (cols 0..63) -> Xs[row][c]; V (cols 128..191) -> Vl
#pragma unroll
  for (int rr = 0; rr < 2; rr++)
#pragma unroll
    for (int f = 0; f < 3; f++) {
      const int c    = (wave * 3 + f) * 16 + l16;
      const int lrow = rr * 16 + quad * 4;
      if (c < 64) {
#pragma unroll
        for (int r = 0; r < 4; r++)
          Xs[lrow + r][c] = (short)f2bf(acc[rr][f][r]);
      } else if (c >= 128) {
        const int d = c - 128;
#pragma unroll
        for (int r = 0; r < 4; r++)
          Vl[d][lrow + r] = (short)f2bf(acc[rr][f][r]);
      }
    }
  __syncthreads();

  // phase B: coalesced Q-frag + V-frag stores (16B per thread each)
  {
    const int s = tid >> 6;          // 0..3
    short8 qv = *(const short8*)&Xs[l32][s * 16 + hl * 8];
    *(short8*)(qfb + (size_t)(b4 * 128 + qw) * 2048 + s * 512 + lane * 8) = qv;
  }
  {
    const int dh = tid >> 7;         // 0..1
    const int s2 = (tid >> 6) & 1;   // 0..1
    short8 vv = *(const short8*)&Vl[dh * 32 + l32][s2 * 16 + hl * 8];
    *(short8*)(vfb + (size_t)(b4 * 64 + kt) * 4096 + dh * 2048 +
               (hsel * 2 + s2) * 512 + lane * 8) = vv;
  }
  __syncthreads();

  // phase C: scatter K (cols 64..127) -> Xs
#pragma unroll
  for (int rr = 0; rr < 2; rr++)
#pragma unroll
    for (int f = 0; f < 3; f++) {
      const int c    = (wave * 3 + f) * 16 + l16;
      const int lrow = rr * 16 + quad * 4;
      if (c >= 64 && c < 128) {
#pragma unroll
        for (int r = 0; r < 4; r++)
          Xs[lrow + r][c - 64] = (short)f2bf(acc[rr][f][r]);
      }
    }
  __syncthreads();

  // phase D: coalesced K-frag store
  {
    const int s = tid >> 6;
    short8 kv = *(const short8*)&Xs[l32][s * 16 + hl * 8];
    *(short8*)(kfb + (size_t)(b4 * 128 + qw) * 2048 + s * 512 + lane * 8) = kv;
  }
}

// ---------------------------------------------------------------------------
// Flash attention. Block = (b, 32 q-rows); 4 waves split the causal key range
// (wave w takes 64-key tiles t = w, w+4, ...). All loads are coalesced
// frag-major dwordx4 from L2. Swapped QK^T -> in-register softmax; P
// redistributed via cvt_pk + permlane32_swap. Fixed-SMAX exp2-domain softmax
// -> wave partials combine by PLAIN SUM in one LDS reduction (no merge pass).
// R3 changes:
//  * CU-balance fix: co-resident blocks are bx and bx+256 (round-robin) ->
//    qw = (u<64) ? 127-u : u-64 makes every such pair sum to 127 tile-units.
//  * Register double-buffer: tile t+4's K/V loads issue BEFORE tile t's
//    compute, hiding the ~200-400cy L2 latency under the ~500cy compute.
// ---------------------------------------------------------------------------
__global__ __launch_bounds__(256) void attn_kernel(
    const unsigned short* __restrict__ qfb, const unsigned short* __restrict__ kfb,
    const unsigned short* __restrict__ vfb, float* __restrict__ out) {
  __shared__ float Ol[4][32][68];
  __shared__ float Ls[4][32];

  const int tid  = threadIdx.x;
  const int wave = tid >> 6;
  const int lane = tid & 63;
  const int l32  = lane & 31;
  const int hl   = lane >> 5;

  const int bx = blockIdx.x;
  const int u  = bx >> 2;
  const int b  = bx & 3;
  const int qw = (u < 64) ? (127 - u) : (u - 64);  // bx/bx+256 pair: sum 127
  const int wq0 = qw * 32;
  const int nt  = (qw >> 1) + 1;     // 64-key tiles covering keys 0..wq0+31

  // Q B-frags (col = l32 = q, k = hl*8+j), resident whole kernel
  short8 qf[4];
  {
    const unsigned short* qp = qfb + (size_t)(b * 128 + qw) * 2048 + lane * 8;
#pragma unroll
    for (int s = 0; s < 4; s++) qf[s] = *(const short8*)(qp + s * 512);
  }

  const unsigned short* kbase = kfb + (size_t)b * 128 * 2048 + lane * 8;
  const unsigned short* vbase = vfb + (size_t)b * 64 * 4096 + lane * 8;

  floatx16 o0, o1;
#pragma unroll
  for (int r = 0; r < 16; r++) { o0[r] = 0.f; o1[r] = 0.f; }
  float ls0 = 0.f, ls1 = 0.f, ls2 = 0.f, ls3 = 0.f;

  auto LOAD = [&](short8* kf, short8* vf, int t) {
    const unsigned short* kp = kbase + (size_t)t * 4096;
    const unsigned short* vp = vbase + (size_t)t * 4096;
#pragma unroll
    for (int sub = 0; sub < 2; sub++)
#pragma unroll
      for (int s = 0; s < 4; s++)
        kf[sub * 4 + s] = *(const short8*)(kp + sub * 2048 + s * 512);
#pragma unroll
    for (int dh = 0; dh < 2; dh++)
#pragma unroll
      for (int s = 0; s < 4; s++)
        vf[dh * 4 + s] = *(const short8*)(vp + dh * 2048 + s * 512);
  };

  auto COMPUTE = [&](const short8* kf, const short8* vf, int k0) {
    // ---- S^T - SMAX = K Q^T + (-SMAX) ----
    floatx16 s0, s1;
#pragma unroll
    for (int r = 0; r < 16; r++) { s0[r] = -SMAX; s1[r] = -SMAX; }
#pragma unroll
    for (int s = 0; s < 4; s++) s0 = mfma32(kf[s], qf[s], s0);
#pragma unroll
    for (int s = 0; s < 4; s++) s1 = mfma32(kf[4 + s], qf[s], s1);

    // causal mask: key = k0 + sub*32 + (r&3) + 8*(r>>2) + 4*hl; q = wq0 + l32
    if (k0 + 63 > wq0) {
      const int dq = k0 + hl * 4 - wq0 - l32;
#pragma unroll
      for (int r = 0; r < 16; r++) {
        const int kl = (r & 3) + 8 * (r >> 2);
        if (dq + kl > 0)      s0[r] = -INFINITY;
        if (dq + kl + 32 > 0) s1[r] = -INFINITY;
      }
    }

    // ---- p = exp2(s - SMAX); per-lane partial denominator ----
#pragma unroll
    for (int r = 0; r < 16; r++) { s0[r] = exp2f(s0[r]); s1[r] = exp2f(s1[r]); }
#pragma unroll
    for (int r = 0; r < 4; r++) {
      ls0 += s0[r]      + s1[r];
      ls1 += s0[r + 4]  + s1[r + 4];
      ls2 += s0[r + 8]  + s1[r + 8];
      ls3 += s0[r + 12] + s1[r + 12];
    }

    // ---- P (C-layout) -> PV A-frags via cvt_pk + permlane32_swap ----
    short8 pa[4];
#pragma unroll
    for (int sb = 0; sb < 2; sb++) {       // S^T sub-tile (keys sb*32..+31)
      const floatx16 sp = sb ? s1 : s0;
#pragma unroll
      for (int ss = 0; ss < 2; ss++) {     // 16-key step within sub-tile
        const int r0 = ss * 8;
        unsigned int x0 = cvtpk(sp[r0 + 0], sp[r0 + 1]);
        unsigned int y0 = cvtpk(sp[r0 + 4], sp[r0 + 5]);
        unsigned int x1 = cvtpk(sp[r0 + 2], sp[r0 + 3]);
        unsigned int y1 = cvtpk(sp[r0 + 6], sp[r0 + 7]);
        asm("v_permlane32_swap_b32 %0, %1" : "+v"(x0), "+v"(y0));
        asm("v_permlane32_swap_b32 %0, %1" : "+v"(x1), "+v"(y1));
        union { unsigned int u[4]; short8 s; } pu;
        pu.u[0] = x0; pu.u[1] = x1; pu.u[2] = y0; pu.u[3] = y1;
        pa[sb * 2 + ss] = pu.s;
      }
    }

    // ---- O += P V ----
#pragma unroll
    for (int s = 0; s < 4; s++) {
      o0 = mfma32(pa[s], vf[s],     o0);
      o1 = mfma32(pa[s], vf[4 + s], o1);
    }
  };

  // two-stage register double-buffer: loads fly one tile ahead of compute
  short8 ka[8], va[8], kb[8], vb[8];
  int t = wave;
  if (t < nt) LOAD(ka, va, t);
  while (t < nt) {
    const int t2 = t + 4;
    if (t2 < nt) LOAD(kb, vb, t2);
    COMPUTE(ka, va, t * 64);
    t += 8;
    if (t < nt) LOAD(ka, va, t);
    if (t2 < nt) COMPUTE(kb, vb, t2 * 64);
  }

  // ---- per-wave denominator (q = l32 in both halves) ----
  float lsum = (ls0 + ls1) + (ls2 + ls3);
  lsum += __shfl_xor(lsum, 32);

  // ---- cross-wave reduction in LDS; write FINAL output ----
#pragma unroll
  for (int r = 0; r < 16; r++) {
    const int qr = (r & 3) + 8 * (r >> 2) + 4 * hl;   // q-local 0..31
    Ol[wave][qr][l32]      = o0[r];
    Ol[wave][qr][32 + l32] = o1[r];
  }
  if (hl == 0) Ls[wave][l32] = lsum;
  __syncthreads();

  const int q  = tid >> 3;          // 0..31
  const int dg = (tid & 7) * 8;     // 0..56
  const float L   = Ls[0][q] + Ls[1][q] + Ls[2][q] + Ls[3][q];
  const float inv = 1.0f / L;
  float4 a = {0.f, 0.f, 0.f, 0.f}, c2 = {0.f, 0.f, 0.f, 0.f};
#pragma unroll
  for (int w = 0; w < 4; w++) {
    const float4 pa4 = *(const float4*)&Ol[w][q][dg];
    const float4 pb4 = *(const float4*)&Ol[w][q][dg + 4];
    a.x  += pa4.x; a.y  += pa4.y; a.z  += pa4.z; a.w  += pa4.w;
    c2.x += pb4.x; c2.y += pb4.y; c2.z += pb4.z; c2.w += pb4.w;
  }
  float* op = out + ((size_t)b * SDIM + wq0 + q) * 64 + dg;
  float4 r0v = {a.x * inv, a.y * inv, a.z * inv, a.w * inv};
  float4 r1v = {c2.x * inv, c2.y * inv, c2.z * inv, c2.w * inv};
  *(float4*)op       = r0v;
  *(float4*)(op + 4) = r1v;
}

extern "C" void kernel_launch(void* const* d_in, const int* in_sizes, int n_in,
                              void* d_out, int out_size, void* d_ws, size_t ws_size,
                              hipStream_t stream) {
  const float* x  = (const float*)d_in[0];
  const float* Wq = (const float*)d_in[1];
  const float* Wk = (const float*)d_in[2];
  const float* Wv = (const float*)d_in[3];
  float* out = (float*)d_out;

  // ws layout: q_frag (2MB) | k_frag (2MB) | v_frag (2MB) | wb (384KB)
  unsigned short* qfb = (unsigned short*)d_ws;
  unsigned short* kfb = qfb + (size_t)1048576;
  unsigned short* vfb = kfb + (size_t)1048576;
  unsigned short* wb  = vfb + (size_t)1048576;

  wcvt_kernel<<<dim3(192), dim3(256), 0, stream>>>(Wq, Wk, Wv, wb);
  proj_kernel<<<dim3(MTOT / 32), dim3(256), 0, stream>>>(x, wb, qfb, kfb, vfb);
  attn_kernel<<<dim3(512), dim3(256), 0, stream>>>(qfb, kfb, vfb, out);
}

// Round 4
// 135.282 us; speedup vs baseline: 1.1105x; 1.1105x over previous
//
#include <hip/hip_runtime.h>
#include <math.h>

#define SDIM 4096
#define DIN  1024
#define DOUT 64
#define BB   4
#define MTOT (BB * SDIM)   // 16384 rows
#define SMAX 12.0f         // fixed softmax max (log2 domain); true max ~8

typedef __attribute__((ext_vector_type(8))) short short8;    // 8 x bf16
typedef __attribute__((ext_vector_type(4))) float floatx4;
typedef __attribute__((ext_vector_type(16))) float floatx16;

static __device__ __forceinline__ unsigned short f2bf(float f) {
  union { float f; unsigned int u; } v; v.f = f;
  unsigned int r = v.u + 0x7fffu + ((v.u >> 16) & 1u);
  return (unsigned short)(r >> 16);
}

static __device__ __forceinline__ floatx4 mfma16(short8 a, short8 b, floatx4 c) {
  return __builtin_amdgcn_mfma_f32_16x16x32_bf16(a, b, c, 0, 0, 0);
}
static __device__ __forceinline__ floatx16 mfma32(short8 a, short8 b, floatx16 c) {
  return __builtin_amdgcn_mfma_f32_32x32x16_bf16(a, b, c, 0, 0, 0);
}
// pack two f32 -> one dword of 2 bf16 (lo = src0)
static __device__ __forceinline__ unsigned int cvtpk(float lo, float hi) {
  unsigned int r;
  asm("v_cvt_pk_bf16_f32 %0, %1, %2" : "=v"(r) : "v"(lo), "v"(hi));
  return r;
}

// ---------------------------------------------------------------------------
// W -> bf16 in B-FRAGMENT-MAJOR layout: element (col=o, k) of the 192x1024
// weight matrix lands at
//   wbf[(((f*8 + k0)*4 + s)*64 + quad*16 + l16)*8 + j]
// where f=o>>4, l16=o&15, k0=k>>7, s=(k>>5)&3, quad=(k>>3)&3, j=k&7.
// proj's B-load for (col-tile f, k-iter k0, s) is then ONE contiguous
// 64-lane x 16B transaction. q scale folds 1/sqrt(64) AND log2(e).
// ---------------------------------------------------------------------------
__global__ __launch_bounds__(256) void wcvt_kernel(
    const float* __restrict__ Wq, const float* __restrict__ Wk,
    const float* __restrict__ Wv, unsigned short* __restrict__ wbf) {
  const int idx  = blockIdx.x * 256 + threadIdx.x;
  const int flat = idx * 4;
  const int m    = flat >> 16;
  const int off  = flat & 65535;
  const float* src = (m == 0) ? Wq : (m == 1) ? Wk : Wv;
  const float  s   = (m == 0) ? 0.125f * 1.44269504f : 1.0f;
  float4 v = *(const float4*)(src + off);
  ushort4 u;
  u.x = f2bf(v.x * s); u.y = f2bf(v.y * s);
  u.z = f2bf(v.z * s); u.w = f2bf(v.w * s);
  const int o    = off >> 10;          // row within this matrix (0..63)
  const int k    = off & 1023;         // 4-aligned
  const int co   = m * 64 + o;         // global col 0..191
  const int f    = co >> 4;
  const int l16  = co & 15;
  const int k0   = k >> 7;
  const int su   = (k >> 5) & 3;
  const int quad = (k >> 3) & 3;
  const int j0   = k & 7;              // 0 or 4
  *(ushort4*)(wbf + (size_t)(((f * 8 + k0) * 4 + su) * 64 + quad * 16 + l16) * 8 + j0) = u;
}

// ---------------------------------------------------------------------------
// Projection: out = x(16384x1024) @ W^T(1024x192), frag-major outputs.
// R4 restructure:
//  * 512 threads/block, K-SPLIT: waves 0-3 do k 0..511, waves 4-7 do
//    k 512..1023 (4 k-iters each), partials reduced via LDS at the end.
//    -> 16 waves/CU (4/SIMD) instead of 8 (2/SIMD).
//  * B-loads from frag-major wbf: one coalesced 512B wave-load each
//    (was 16 scattered cache lines).
//  * LDS double-buffer + 2-deep x register prefetch: ONE barrier per
//    k-iter (5 total vs 16) and HBM latency hides under the MFMA phase.
// Output frag layouts (consumed by attn_kernel) unchanged:
//   Q/K frag: buf[(b*128+blk)*2048 + s*512 + lane*8 + j]
//             = elem(row = blk*32 + (lane&31), d = s*16 + (lane>>5)*8 + j)
//   V   frag: buf[(b*64+kt)*4096 + dh*2048 + s*512 + lane*8 + j]
//             = V(key = kt*64 + s*16 + (lane>>5)*8 + j, d = dh*32 + (lane&31))
// ---------------------------------------------------------------------------
__global__ __launch_bounds__(512, 4) void proj_kernel(
    const float* __restrict__ x, const unsigned short* __restrict__ wbf,
    unsigned short* __restrict__ qfb, unsigned short* __restrict__ kfb,
    unsigned short* __restrict__ vfb) {
  __shared__ __align__(16) short Xs[2][2][32][136];  // [khalf][dbuf][row][k]
  __shared__ __align__(16) short Vl[64][40];         // V^T tile [d][seq_local]
  __shared__ float Rs[6144];                         // k-half reduction (24KB)

  const int tid  = threadIdx.x;
  const int h    = tid >> 8;        // k-half 0/1
  const int t8   = tid & 255;
  const int wave = tid >> 6;        // 0..7
  const int w4   = wave & 3;        // wave within half
  const int lane = tid & 63;
  const int quad = lane >> 4;
  const int l16  = lane & 15;
  const int l32  = lane & 31;
  const int hl   = (lane >> 5) & 1;
  const int row0 = blockIdx.x * 32;

  floatx4 acc[2][3];
#pragma unroll
  for (int i = 0; i < 2; i++)
#pragma unroll
    for (int j = 0; j < 3; j++) acc[i][j] = floatx4{0, 0, 0, 0};

  const int sr = t8 >> 3;           // staging row 0..31
  const int sc = (t8 & 7) * 16;     // staging col (floats)
  const float* xbase = x + (size_t)(row0 + sr) * DIN + h * 512 + sc;

  float4 xa0[4], xa1[4];            // reg sets: iter j lives in set j&1
  // prologue: load iter0, stage buf0, load iter1
#pragma unroll
  for (int i = 0; i < 4; i++) xa0[i] = *(const float4*)(xbase + i * 4);
  {
    short8 p0, p1;
#pragma unroll
    for (int i = 0; i < 4; i++) {
      p0[i]     = f2bf(xa0[0][i]); p0[i + 4] = f2bf(xa0[1][i]);
      p1[i]     = f2bf(xa0[2][i]); p1[i + 4] = f2bf(xa0[3][i]);
    }
    *(short8*)&Xs[h][0][sr][sc]     = p0;
    *(short8*)&Xs[h][0][sr][sc + 8] = p1;
  }
#pragma unroll
  for (int i = 0; i < 4; i++) xa1[i] = *(const float4*)(xbase + 128 + i * 4);
  __syncthreads();

#pragma unroll
  for (int it = 0; it < 4; ++it) {
    const int cb = it & 1;
    // prefetch x for iter it+2 into the set just freed (set cb)
    if (it + 2 < 4) {
      const float* xp = xbase + (it + 2) * 128;
#pragma unroll
      for (int i = 0; i < 4; i++) {
        float4 t = *(const float4*)(xp + i * 4);
        if (cb == 0) xa0[i] = t; else xa1[i] = t;
      }
    }
    // stage iter it+1 into the other buffer (overlaps compute of buf cb)
    if (it + 1 < 4) {
      short8 p0, p1;
#pragma unroll
      for (int i = 0; i < 4; i++) {
        float4 sA = (cb == 0) ? xa1[i] : xa0[i];
        (void)sA;
      }
#pragma unroll
      for (int i = 0; i < 4; i++) {
        const float4 a = (cb == 0) ? xa1[i] : xa0[i];
        if (i == 0) { p0[0] = f2bf(a[0]); p0[1] = f2bf(a[1]); p0[2] = f2bf(a[2]); p0[3] = f2bf(a[3]); }
        if (i == 1) { p0[4] = f2bf(a[0]); p0[5] = f2bf(a[1]); p0[6] = f2bf(a[2]); p0[7] = f2bf(a[3]); }
        if (i == 2) { p1[0] = f2bf(a[0]); p1[1] = f2bf(a[1]); p1[2] = f2bf(a[2]); p1[3] = f2bf(a[3]); }
        if (i == 3) { p1[4] = f2bf(a[0]); p1[5] = f2bf(a[1]); p1[6] = f2bf(a[2]); p1[7] = f2bf(a[3]); }
      }
      *(short8*)&Xs[h][cb ^ 1][sr][sc]     = p0;
      *(short8*)&Xs[h][cb ^ 1][sr][sc + 8] = p1;
    }
    // compute from buffer cb
#pragma unroll
    for (int s = 0; s < 4; s++) {
      const short8 a0 = *(const short8*)&Xs[h][cb][l16][s * 32 + quad * 8];
      const short8 a1 = *(const short8*)&Xs[h][cb][16 + l16][s * 32 + quad * 8];
#pragma unroll
      for (int f = 0; f < 3; f++) {
        const int ct = w4 * 3 + f;
        const short8 b = *(const short8*)(
            wbf + (size_t)(((ct * 8 + (h * 4 + it)) * 4 + s) * 64 + lane) * 8);
        acc[0][f] = mfma16(a0, b, acc[0][f]);
        acc[1][f] = mfma16(a1, b, acc[1][f]);
      }
    }
    __syncthreads();
  }

  // ---- k-half reduction: waves 4-7 -> LDS, waves 0-3 accumulate ----
  if (h == 1) {
#pragma unroll
    for (int rr = 0; rr < 2; rr++)
#pragma unroll
      for (int f = 0; f < 3; f++)
#pragma unroll
        for (int r = 0; r < 4; r++)
          Rs[(((w4 * 2 + rr) * 3 + f) * 4 + r) * 64 + lane] = acc[rr][f][r];
  }
  __syncthreads();
  if (h == 0) {
#pragma unroll
    for (int rr = 0; rr < 2; rr++)
#pragma unroll
      for (int f = 0; f < 3; f++)
#pragma unroll
        for (int r = 0; r < 4; r++)
          acc[rr][f][r] += Rs[(((w4 * 2 + rr) * 3 + f) * 4 + r) * 64 + lane];
  }

  // ---- epilogue: LDS re-layout -> fragment-major coalesced stores ----
  const int b4   = row0 >> 12;       // batch
  const int seq  = row0 & 4095;      // seq offset within batch
  const int qw   = seq >> 5;         // 32-row block index 0..127
  const int kt   = seq >> 6;         // 64-key tile index 0..63
  const int hsel = (seq >> 5) & 1;   // which half of the 64-key tile

  short (*Qs)[136] = Xs[0][0];       // reuse staging LDS for Q/K scatter

  // phase A: h==0 scatters Q (cols 0..63) -> Qs; V (cols 128..191) -> Vl
  if (h == 0) {
#pragma unroll
    for (int rr = 0; rr < 2; rr++)
#pragma unroll
      for (int f = 0; f < 3; f++) {
        const int c    = (w4 * 3 + f) * 16 + l16;
        const int lrow = rr * 16 + quad * 4;
        if (c < 64) {
#pragma unroll
          for (int r = 0; r < 4; r++)
            Qs[lrow + r][c] = (short)f2bf(acc[rr][f][r]);
        } else if (c >= 128) {
          const int d = c - 128;
#pragma unroll
          for (int r = 0; r < 4; r++)
            Vl[d][lrow + r] = (short)f2bf(acc[rr][f][r]);
        }
      }
  }
  __syncthreads();

  // phase B: Q-frag store (threads 0-255) + V-frag store (threads 256-511)
  if (h == 0) {
    const int s = t8 >> 6;           // 0..3
    short8 qv = *(const short8*)&Qs[l32][s * 16 + hl * 8];
    *(short8*)(qfb + (size_t)(b4 * 128 + qw) * 2048 + s * 512 + (t8 & 63) * 8) = qv;
  } else {
    const int dh = t8 >> 7;          // 0..1
    const int s2 = (t8 >> 6) & 1;    // 0..1
    short8 vv = *(const short8*)&Vl[dh * 32 + l32][s2 * 16 + hl * 8];
    *(short8*)(vfb + (size_t)(b4 * 64 + kt) * 4096 + dh * 2048 +
               (hsel * 2 + s2) * 512 + (t8 & 63) * 8) = vv;
  }
  __syncthreads();

  // phase C: h==0 scatters K (cols 64..127) -> Qs
  if (h == 0) {
#pragma unroll
    for (int rr = 0; rr < 2; rr++)
#pragma unroll
      for (int f = 0; f < 3; f++) {
        const int c    = (w4 * 3 + f) * 16 + l16;
        const int lrow = rr * 16 + quad * 4;
        if (c >= 64 && c < 128) {
#pragma unroll
          for (int r = 0; r < 4; r++)
            Qs[lrow + r][c - 64] = (short)f2bf(acc[rr][f][r]);
        }
      }
  }
  __syncthreads();

  // phase D: coalesced K-frag store (threads 0-255)
  if (h == 0) {
    const int s = t8 >> 6;
    short8 kv = *(const short8*)&Qs[l32][s * 16 + hl * 8];
    *(short8*)(kfb + (size_t)(b4 * 128 + qw) * 2048 + s * 512 + (t8 & 63) * 8) = kv;
  }
}

// ---------------------------------------------------------------------------
// Flash attention (unchanged from R3 — verified). Block = (b, 32 q-rows);
// 4 waves split the causal key range; coalesced frag-major dwordx4 loads;
// swapped QK^T -> in-register softmax; cvt_pk+permlane32_swap P
// redistribution; fixed-SMAX exp2-domain softmax -> plain-sum LDS merge.
// ---------------------------------------------------------------------------
__global__ __launch_bounds__(256) void attn_kernel(
    const unsigned short* __restrict__ qfb, const unsigned short* __restrict__ kfb,
    const unsigned short* __restrict__ vfb, float* __restrict__ out) {
  __shared__ float Ol[4][32][68];
  __shared__ float Ls[4][32];

  const int tid  = threadIdx.x;
  const int wave = tid >> 6;
  const int lane = tid & 63;
  const int l32  = lane & 31;
  const int hl   = lane >> 5;

  const int bx = blockIdx.x;
  const int u  = bx >> 2;
  const int b  = bx & 3;
  const int qw = (u < 64) ? (127 - u) : (u - 64);  // bx/bx+256 pair: sum 127
  const int wq0 = qw * 32;
  const int nt  = (qw >> 1) + 1;     // 64-key tiles covering keys 0..wq0+31

  // Q B-frags (col = l32 = q, k = hl*8+j), resident whole kernel
  short8 qf[4];
  {
    const unsigned short* qp = qfb + (size_t)(b * 128 + qw) * 2048 + lane * 8;
#pragma unroll
    for (int s = 0; s < 4; s++) qf[s] = *(const short8*)(qp + s * 512);
  }

  const unsigned short* kbase = kfb + (size_t)b * 128 * 2048 + lane * 8;
  const unsigned short* vbase = vfb + (size_t)b * 64 * 4096 + lane * 8;

  floatx16 o0, o1;
#pragma unroll
  for (int r = 0; r < 16; r++) { o0[r] = 0.f; o1[r] = 0.f; }
  float ls0 = 0.f, ls1 = 0.f, ls2 = 0.f, ls3 = 0.f;

  auto LOAD = [&](short8* kf, short8* vf, int t) {
    const unsigned short* kp = kbase + (size_t)t * 4096;
    const unsigned short* vp = vbase + (size_t)t * 4096;
#pragma unroll
    for (int sub = 0; sub < 2; sub++)
#pragma unroll
      for (int s = 0; s < 4; s++)
        kf[sub * 4 + s] = *(const short8*)(kp + sub * 2048 + s * 512);
#pragma unroll
    for (int dh = 0; dh < 2; dh++)
#pragma unroll
      for (int s = 0; s < 4; s++)
        vf[dh * 4 + s] = *(const short8*)(vp + dh * 2048 + s * 512);
  };

  auto COMPUTE = [&](const short8* kf, const short8* vf, int k0) {
    // ---- S^T - SMAX = K Q^T + (-SMAX) ----
    floatx16 s0, s1;
#pragma unroll
    for (int r = 0; r < 16; r++) { s0[r] = -SMAX; s1[r] = -SMAX; }
#pragma unroll
    for (int s = 0; s < 4; s++) s0 = mfma32(kf[s], qf[s], s0);
#pragma unroll
    for (int s = 0; s < 4; s++) s1 = mfma32(kf[4 + s], qf[s], s1);

    // causal mask: key = k0 + sub*32 + (r&3) + 8*(r>>2) + 4*hl; q = wq0 + l32
    if (k0 + 63 > wq0) {
      const int dq = k0 + hl * 4 - wq0 - l32;
#pragma unroll
      for (int r = 0; r < 16; r++) {
        const int kl = (r & 3) + 8 * (r >> 2);
        if (dq + kl > 0)      s0[r] = -INFINITY;
        if (dq + kl + 32 > 0) s1[r] = -INFINITY;
      }
    }

    // ---- p = exp2(s - SMAX); per-lane partial denominator ----
#pragma unroll
    for (int r = 0; r < 16; r++) { s0[r] = exp2f(s0[r]); s1[r] = exp2f(s1[r]); }
#pragma unroll
    for (int r = 0; r < 4; r++) {
      ls0 += s0[r]      + s1[r];
      ls1 += s0[r + 4]  + s1[r + 4];
      ls2 += s0[r + 8]  + s1[r + 8];
      ls3 += s0[r + 12] + s1[r + 12];
    }

    // ---- P (C-layout) -> PV A-frags via cvt_pk + permlane32_swap ----
    short8 pa[4];
#pragma unroll
    for (int sb = 0; sb < 2; sb++) {       // S^T sub-tile (keys sb*32..+31)
      const floatx16 sp = sb ? s1 : s0;
#pragma unroll
      for (int ss = 0; ss < 2; ss++) {     // 16-key step within sub-tile
        const int r0 = ss * 8;
        unsigned int x0 = cvtpk(sp[r0 + 0], sp[r0 + 1]);
        unsigned int y0 = cvtpk(sp[r0 + 4], sp[r0 + 5]);
        unsigned int x1 = cvtpk(sp[r0 + 2], sp[r0 + 3]);
        unsigned int y1 = cvtpk(sp[r0 + 6], sp[r0 + 7]);
        asm("v_permlane32_swap_b32 %0, %1" : "+v"(x0), "+v"(y0));
        asm("v_permlane32_swap_b32 %0, %1" : "+v"(x1), "+v"(y1));
        union { unsigned int u[4]; short8 s; } pu;
        pu.u[0] = x0; pu.u[1] = x1; pu.u[2] = y0; pu.u[3] = y1;
        pa[sb * 2 + ss] = pu.s;
      }
    }

    // ---- O += P V ----
#pragma unroll
    for (int s = 0; s < 4; s++) {
      o0 = mfma32(pa[s], vf[s],     o0);
      o1 = mfma32(pa[s], vf[4 + s], o1);
    }
  };

  // two-stage register double-buffer: loads fly one tile ahead of compute
  short8 ka[8], va[8], kb[8], vb[8];
  int t = wave;
  if (t < nt) LOAD(ka, va, t);
  while (t < nt) {
    const int t2 = t + 4;
    if (t2 < nt) LOAD(kb, vb, t2);
    COMPUTE(ka, va, t * 64);
    t += 8;
    if (t < nt) LOAD(ka, va, t);
    if (t2 < nt) COMPUTE(kb, vb, t2 * 64);
  }

  // ---- per-wave denominator (q = l32 in both halves) ----
  float lsum = (ls0 + ls1) + (ls2 + ls3);
  lsum += __shfl_xor(lsum, 32);

  // ---- cross-wave reduction in LDS; write FINAL output ----
#pragma unroll
  for (int r = 0; r < 16; r++) {
    const int qr = (r & 3) + 8 * (r >> 2) + 4 * hl;   // q-local 0..31
    Ol[wave][qr][l32]      = o0[r];
    Ol[wave][qr][32 + l32] = o1[r];
  }
  if (hl == 0) Ls[wave][l32] = lsum;
  __syncthreads();

  const int q  = tid >> 3;          // 0..31
  const int dg = (tid & 7) * 8;     // 0..56
  const float L   = Ls[0][q] + Ls[1][q] + Ls[2][q] + Ls[3][q];
  const float inv = 1.0f / L;
  float4 a = {0.f, 0.f, 0.f, 0.f}, c2 = {0.f, 0.f, 0.f, 0.f};
#pragma unroll
  for (int w = 0; w < 4; w++) {
    const float4 pa4 = *(const float4*)&Ol[w][q][dg];
    const float4 pb4 = *(const float4*)&Ol[w][q][dg + 4];
    a.x  += pa4.x; a.y  += pa4.y; a.z  += pa4.z; a.w  += pa4.w;
    c2.x += pb4.x; c2.y += pb4.y; c2.z += pb4.z; c2.w += pb4.w;
  }
  float* op = out + ((size_t)b * SDIM + wq0 + q) * 64 + dg;
  float4 r0v = {a.x * inv, a.y * inv, a.z * inv, a.w * inv};
  float4 r1v = {c2.x * inv, c2.y * inv, c2.z * inv, c2.w * inv};
  *(float4*)op       = r0v;
  *(float4*)(op + 4) = r1v;
}

extern "C" void kernel_launch(void* const* d_in, const int* in_sizes, int n_in,
                              void* d_out, int out_size, void* d_ws, size_t ws_size,
                              hipStream_t stream) {
  const float* x  = (const float*)d_in[0];
  const float* Wq = (const float*)d_in[1];
  const float* Wk = (const float*)d_in[2];
  const float* Wv = (const float*)d_in[3];
  float* out = (float*)d_out;

  // ws layout: q_frag (2MB) | k_frag (2MB) | v_frag (2MB) | wbf (384KB)
  unsigned short* qfb = (unsigned short*)d_ws;
  unsigned short* kfb = qfb + (size_t)1048576;
  unsigned short* vfb = kfb + (size_t)1048576;
  unsigned short* wbf = vfb + (size_t)1048576;

  wcvt_kernel<<<dim3(192), dim3(256), 0, stream>>>(Wq, Wk, Wv, wbf);
  proj_kernel<<<dim3(MTOT / 32), dim3(512), 0, stream>>>(x, wbf, qfb, kfb, vfb);
  attn_kernel<<<dim3(512), dim3(256), 0, stream>>>(qfb, kfb, vfb, out);
}

// Round 5
// 126.381 us; speedup vs baseline: 1.1887x; 1.0704x over previous
//
#include <hip/hip_runtime.h>
#include <math.h>

#define SDIM 4096
#define DIN  1024
#define DOUT 64
#define BB   4
#define MTOT (BB * SDIM)   // 16384 rows
#define SMAX 12.0f         // fixed softmax max (log2 domain); true max ~8

typedef __attribute__((ext_vector_type(8))) short short8;    // 8 x bf16
typedef __attribute__((ext_vector_type(4))) float floatx4;
typedef __attribute__((ext_vector_type(16))) float floatx16;

static __device__ __forceinline__ unsigned short f2bf(float f) {
  union { float f; unsigned int u; } v; v.f = f;
  unsigned int r = v.u + 0x7fffu + ((v.u >> 16) & 1u);
  return (unsigned short)(r >> 16);
}

static __device__ __forceinline__ floatx4 mfma16(short8 a, short8 b, floatx4 c) {
  return __builtin_amdgcn_mfma_f32_16x16x32_bf16(a, b, c, 0, 0, 0);
}
static __device__ __forceinline__ floatx16 mfma32(short8 a, short8 b, floatx16 c) {
  return __builtin_amdgcn_mfma_f32_32x32x16_bf16(a, b, c, 0, 0, 0);
}
// pack two f32 -> one dword of 2 bf16 (lo = src0)
static __device__ __forceinline__ unsigned int cvtpk(float lo, float hi) {
  unsigned int r;
  asm("v_cvt_pk_bf16_f32 %0, %1, %2" : "=v"(r) : "v"(lo), "v"(hi));
  return r;
}

// ---------------------------------------------------------------------------
// W -> bf16 in B-FRAGMENT-MAJOR layout: element (col=o, k) of the 192x1024
// weight matrix lands at
//   wbf[(((f*8 + k0)*4 + s)*64 + quad*16 + l16)*8 + j]
// where f=o>>4, l16=o&15, k0=k>>7, s=(k>>5)&3, quad=(k>>3)&3, j=k&7.
// proj's B-load for (col-tile f, k-iter k0, s) is then ONE contiguous
// 64-lane x 16B transaction. q scale folds 1/sqrt(64) AND log2(e).
// ---------------------------------------------------------------------------
__global__ __launch_bounds__(256) void wcvt_kernel(
    const float* __restrict__ Wq, const float* __restrict__ Wk,
    const float* __restrict__ Wv, unsigned short* __restrict__ wbf) {
  const int idx  = blockIdx.x * 256 + threadIdx.x;
  const int flat = idx * 4;
  const int m    = flat >> 16;
  const int off  = flat & 65535;
  const float* src = (m == 0) ? Wq : (m == 1) ? Wk : Wv;
  const float  s   = (m == 0) ? 0.125f * 1.44269504f : 1.0f;
  float4 v = *(const float4*)(src + off);
  ushort4 u;
  u.x = f2bf(v.x * s); u.y = f2bf(v.y * s);
  u.z = f2bf(v.z * s); u.w = f2bf(v.w * s);
  const int o    = off >> 10;          // row within this matrix (0..63)
  const int k    = off & 1023;         // 4-aligned
  const int co   = m * 64 + o;         // global col 0..191
  const int f    = co >> 4;
  const int l16  = co & 15;
  const int k0   = k >> 7;
  const int su   = (k >> 5) & 3;
  const int quad = (k >> 3) & 3;
  const int j0   = k & 7;              // 0 or 4
  *(ushort4*)(wbf + (size_t)(((f * 8 + k0) * 4 + su) * 64 + quad * 16 + l16) * 8 + j0) = u;
}

// ---------------------------------------------------------------------------
// Projection: out = x(16384x1024) @ W^T(1024x192), frag-major outputs.
// R5: ALL x loads hoisted to kernel start (16 dwordx4/thread in flight at
// once -> one HBM latency exposure, maximal MLP); launch_bounds(512,2)
// uncaps the register allocator (xa[4][4] = 64 VGPR held) so nothing spills.
// Loop body is pure LDS-stage + 24 MFMA per iter.
// Output frag layouts (consumed by attn_kernel) unchanged:
//   Q/K frag: buf[(b*128+blk)*2048 + s*512 + lane*8 + j]
//             = elem(row = blk*32 + (lane&31), d = s*16 + (lane>>5)*8 + j)
//   V   frag: buf[(b*64+kt)*4096 + dh*2048 + s*512 + lane*8 + j]
//             = V(key = kt*64 + s*16 + (lane>>5)*8 + j, d = dh*32 + (lane&31))
// ---------------------------------------------------------------------------
#define PROJ_STAGE(IT, DB) do {                                               \
    short8 p0_, p1_;                                                          \
    _Pragma("unroll") for (int i = 0; i < 4; i++) {                           \
      p0_[i]     = f2bf(xa[IT][0][i]); p0_[i + 4] = f2bf(xa[IT][1][i]);       \
      p1_[i]     = f2bf(xa[IT][2][i]); p1_[i + 4] = f2bf(xa[IT][3][i]);       \
    }                                                                         \
    *(short8*)&Xs[h][DB][sr][sc]     = p0_;                                   \
    *(short8*)&Xs[h][DB][sr][sc + 8] = p1_;                                   \
  } while (0)

__global__ __launch_bounds__(512, 2) void proj_kernel(
    const float* __restrict__ x, const unsigned short* __restrict__ wbf,
    unsigned short* __restrict__ qfb, unsigned short* __restrict__ kfb,
    unsigned short* __restrict__ vfb) {
  __shared__ __align__(16) short Xs[2][2][32][136];  // [khalf][dbuf][row][k]
  __shared__ __align__(16) short Vl[64][40];         // V^T tile [d][seq_local]
  __shared__ float Rs[6144];                         // k-half reduction (24KB)

  const int tid  = threadIdx.x;
  const int h    = tid >> 8;        // k-half 0/1
  const int t8   = tid & 255;
  const int wave = tid >> 6;        // 0..7
  const int w4   = wave & 3;        // wave within half
  const int lane = tid & 63;
  const int quad = lane >> 4;
  const int l16  = lane & 15;
  const int l32  = lane & 31;
  const int hl   = (lane >> 5) & 1;
  const int row0 = blockIdx.x * 32;

  floatx4 acc[2][3];
#pragma unroll
  for (int i = 0; i < 2; i++)
#pragma unroll
    for (int j = 0; j < 3; j++) acc[i][j] = floatx4{0, 0, 0, 0};

  const int sr = t8 >> 3;           // staging row 0..31
  const int sc = (t8 & 7) * 16;     // staging col (floats)
  const float* xbase = x + (size_t)(row0 + sr) * DIN + h * 512 + sc;

  // ---- hoist ALL x loads: 16 dwordx4 in flight, one latency exposure ----
  float4 xa[4][4];
#pragma unroll
  for (int it = 0; it < 4; it++)
#pragma unroll
    for (int i = 0; i < 4; i++)
      xa[it][i] = *(const float4*)(xbase + it * 128 + i * 4);

  PROJ_STAGE(0, 0);
  __syncthreads();

#pragma unroll
  for (int it = 0; it < 4; ++it) {
    const int cb = it & 1;
    // stage iter it+1 into the other buffer (overlaps compute of buf cb)
    if (it == 0) PROJ_STAGE(1, 1);
    else if (it == 1) PROJ_STAGE(2, 0);
    else if (it == 2) PROJ_STAGE(3, 1);
    // compute from buffer cb
#pragma unroll
    for (int s = 0; s < 4; s++) {
      const short8 a0 = *(const short8*)&Xs[h][cb][l16][s * 32 + quad * 8];
      const short8 a1 = *(const short8*)&Xs[h][cb][16 + l16][s * 32 + quad * 8];
#pragma unroll
      for (int f = 0; f < 3; f++) {
        const int ct = w4 * 3 + f;
        const short8 b = *(const short8*)(
            wbf + (size_t)(((ct * 8 + (h * 4 + it)) * 4 + s) * 64 + lane) * 8);
        acc[0][f] = mfma16(a0, b, acc[0][f]);
        acc[1][f] = mfma16(a1, b, acc[1][f]);
      }
    }
    __syncthreads();
  }

  // ---- k-half reduction: waves 4-7 -> LDS, waves 0-3 accumulate ----
  if (h == 1) {
#pragma unroll
    for (int rr = 0; rr < 2; rr++)
#pragma unroll
      for (int f = 0; f < 3; f++)
#pragma unroll
        for (int r = 0; r < 4; r++)
          Rs[(((w4 * 2 + rr) * 3 + f) * 4 + r) * 64 + lane] = acc[rr][f][r];
  }
  __syncthreads();
  if (h == 0) {
#pragma unroll
    for (int rr = 0; rr < 2; rr++)
#pragma unroll
      for (int f = 0; f < 3; f++)
#pragma unroll
        for (int r = 0; r < 4; r++)
          acc[rr][f][r] += Rs[(((w4 * 2 + rr) * 3 + f) * 4 + r) * 64 + lane];
  }

  // ---- epilogue: LDS re-layout -> fragment-major coalesced stores ----
  const int b4   = row0 >> 12;       // batch
  const int seq  = row0 & 4095;      // seq offset within batch
  const int qw   = seq >> 5;         // 32-row block index 0..127
  const int kt   = seq >> 6;         // 64-key tile index 0..63
  const int hsel = (seq >> 5) & 1;   // which half of the 64-key tile

  short (*Qs)[136] = Xs[0][0];       // reuse staging LDS for Q/K scatter

  // phase A: h==0 scatters Q (cols 0..63) -> Qs; V (cols 128..191) -> Vl
  if (h == 0) {
#pragma unroll
    for (int rr = 0; rr < 2; rr++)
#pragma unroll
      for (int f = 0; f < 3; f++) {
        const int c    = (w4 * 3 + f) * 16 + l16;
        const int lrow = rr * 16 + quad * 4;
        if (c < 64) {
#pragma unroll
          for (int r = 0; r < 4; r++)
            Qs[lrow + r][c] = (short)f2bf(acc[rr][f][r]);
        } else if (c >= 128) {
          const int d = c - 128;
#pragma unroll
          for (int r = 0; r < 4; r++)
            Vl[d][lrow + r] = (short)f2bf(acc[rr][f][r]);
        }
      }
  }
  __syncthreads();

  // phase B: Q-frag store (threads 0-255) + V-frag store (threads 256-511)
  if (h == 0) {
    const int s = t8 >> 6;           // 0..3
    short8 qv = *(const short8*)&Qs[l32][s * 16 + hl * 8];
    *(short8*)(qfb + (size_t)(b4 * 128 + qw) * 2048 + s * 512 + (t8 & 63) * 8) = qv;
  } else {
    const int dh = t8 >> 7;          // 0..1
    const int s2 = (t8 >> 6) & 1;    // 0..1
    short8 vv = *(const short8*)&Vl[dh * 32 + l32][s2 * 16 + hl * 8];
    *(short8*)(vfb + (size_t)(b4 * 64 + kt) * 4096 + dh * 2048 +
               (hsel * 2 + s2) * 512 + (t8 & 63) * 8) = vv;
  }
  __syncthreads();

  // phase C: h==0 scatters K (cols 64..127) -> Qs
  if (h == 0) {
#pragma unroll
    for (int rr = 0; rr < 2; rr++)
#pragma unroll
      for (int f = 0; f < 3; f++) {
        const int c    = (w4 * 3 + f) * 16 + l16;
        const int lrow = rr * 16 + quad * 4;
        if (c >= 64 && c < 128) {
#pragma unroll
          for (int r = 0; r < 4; r++)
            Qs[lrow + r][c - 64] = (short)f2bf(acc[rr][f][r]);
        }
      }
  }
  __syncthreads();

  // phase D: coalesced K-frag store (threads 0-255)
  if (h == 0) {
    const int s = t8 >> 6;
    short8 kv = *(const short8*)&Qs[l32][s * 16 + hl * 8];
    *(short8*)(kfb + (size_t)(b4 * 128 + qw) * 2048 + s * 512 + (t8 & 63) * 8) = kv;
  }
}

// ---------------------------------------------------------------------------
// Flash attention. Block = (b, 32 q-rows); 4 waves split the causal key range
// (wave w takes 64-key tiles t = w, w+4, ...). All loads are coalesced
// frag-major dwordx4 from L2. Swapped QK^T -> in-register softmax; P
// redistributed via cvt_pk + permlane32_swap; fixed-SMAX exp2-domain softmax
// -> wave partials merge by PLAIN SUM in one LDS reduction.
// R5: __launch_bounds__(256, 2) -> VGPR budget 256: the whole tile state
// (~230 regs incl. 2-deep K/V double-buffer) stays in registers. Previous
// rounds ran with a ~100-VGPR occupancy-heuristic cap -> per-tile scratch
// spills were the 4850 cy/tile mystery. Lambdas replaced by macros over
// statically-indexed named arrays (rule #20: no pointer-indexed demotion).
// ---------------------------------------------------------------------------
#define ATTN_LOAD(KF, VF, T) do {                                             \
    const unsigned short* kp_ = kbase + (size_t)(T) * 4096;                   \
    const unsigned short* vp_ = vbase + (size_t)(T) * 4096;                   \
    _Pragma("unroll") for (int s = 0; s < 4; s++)                             \
      KF[s]     = *(const short8*)(kp_ + s * 512);                            \
    _Pragma("unroll") for (int s = 0; s < 4; s++)                             \
      KF[4 + s] = *(const short8*)(kp_ + 2048 + s * 512);                     \
    _Pragma("unroll") for (int s = 0; s < 4; s++)                             \
      VF[s]     = *(const short8*)(vp_ + s * 512);                            \
    _Pragma("unroll") for (int s = 0; s < 4; s++)                             \
      VF[4 + s] = *(const short8*)(vp_ + 2048 + s * 512);                     \
  } while (0)

#define ATTN_TILE(KF, VF, K0) do {                                            \
    floatx16 s0_, s1_;                                                        \
    _Pragma("unroll") for (int r = 0; r < 16; r++) {                          \
      s0_[r] = -SMAX; s1_[r] = -SMAX; }                                       \
    _Pragma("unroll") for (int s = 0; s < 4; s++)                             \
      s0_ = mfma32(KF[s], qf[s], s0_);                                        \
    _Pragma("unroll") for (int s = 0; s < 4; s++)                             \
      s1_ = mfma32(KF[4 + s], qf[s], s1_);                                    \
    if ((K0) + 63 > wq0) {                                                    \
      const int dq_ = (K0) + hl * 4 - wq0 - l32;                              \
      _Pragma("unroll") for (int r = 0; r < 16; r++) {                        \
        const int kl_ = (r & 3) + 8 * (r >> 2);                               \
        if (dq_ + kl_ > 0)      s0_[r] = -INFINITY;                           \
        if (dq_ + kl_ + 32 > 0) s1_[r] = -INFINITY;                           \
      }                                                                       \
    }                                                                         \
    _Pragma("unroll") for (int r = 0; r < 16; r++) {                          \
      s0_[r] = exp2f(s0_[r]); s1_[r] = exp2f(s1_[r]); }                       \
    _Pragma("unroll") for (int r = 0; r < 4; r++) {                           \
      ls0 += s0_[r]      + s1_[r];                                            \
      ls1 += s0_[r + 4]  + s1_[r + 4];                                        \
      ls2 += s0_[r + 8]  + s1_[r + 8];                                        \
      ls3 += s0_[r + 12] + s1_[r + 12]; }                                     \
    short8 pa_[4];                                                            \
    _Pragma("unroll") for (int ss = 0; ss < 2; ss++) {                        \
      const int r0_ = ss * 8;                                                 \
      unsigned int x0_ = cvtpk(s0_[r0_ + 0], s0_[r0_ + 1]);                   \
      unsigned int y0_ = cvtpk(s0_[r0_ + 4], s0_[r0_ + 5]);                   \
      unsigned int x1_ = cvtpk(s0_[r0_ + 2], s0_[r0_ + 3]);                   \
      unsigned int y1_ = cvtpk(s0_[r0_ + 6], s0_[r0_ + 7]);                   \
      asm("v_permlane32_swap_b32 %0, %1" : "+v"(x0_), "+v"(y0_));             \
      asm("v_permlane32_swap_b32 %0, %1" : "+v"(x1_), "+v"(y1_));             \
      union { unsigned int u[4]; short8 s; } pu_;                             \
      pu_.u[0] = x0_; pu_.u[1] = x1_; pu_.u[2] = y0_; pu_.u[3] = y1_;         \
      pa_[ss] = pu_.s;                                                        \
    }                                                                         \
    _Pragma("unroll") for (int ss = 0; ss < 2; ss++) {                        \
      const int r0_ = ss * 8;                                                 \
      unsigned int x0_ = cvtpk(s1_[r0_ + 0], s1_[r0_ + 1]);                   \
      unsigned int y0_ = cvtpk(s1_[r0_ + 4], s1_[r0_ + 5]);                   \
      unsigned int x1_ = cvtpk(s1_[r0_ + 2], s1_[r0_ + 3]);                   \
      unsigned int y1_ = cvtpk(s1_[r0_ + 6], s1_[r0_ + 7]);                   \
      asm("v_permlane32_swap_b32 %0, %1" : "+v"(x0_), "+v"(y0_));             \
      asm("v_permlane32_swap_b32 %0, %1" : "+v"(x1_), "+v"(y1_));             \
      union { unsigned int u[4]; short8 s; } pu_;                             \
      pu_.u[0] = x0_; pu_.u[1] = x1_; pu_.u[2] = y0_; pu_.u[3] = y1_;         \
      pa_[2 + ss] = pu_.s;                                                    \
    }                                                                         \
    _Pragma("unroll") for (int s = 0; s < 4; s++) {                           \
      o0 = mfma32(pa_[s], VF[s],     o0);                                     \
      o1 = mfma32(pa_[s], VF[4 + s], o1);                                     \
    }                                                                         \
  } while (0)

__global__ __launch_bounds__(256, 2) void attn_kernel(
    const unsigned short* __restrict__ qfb, const unsigned short* __restrict__ kfb,
    const unsigned short* __restrict__ vfb, float* __restrict__ out) {
  __shared__ float Ol[4][32][68];
  __shared__ float Ls[4][32];

  const int tid  = threadIdx.x;
  const int wave = tid >> 6;
  const int lane = tid & 63;
  const int l32  = lane & 31;
  const int hl   = lane >> 5;

  const int bx = blockIdx.x;
  const int u  = bx >> 2;
  const int b  = bx & 3;
  const int qw = (u < 64) ? (127 - u) : (u - 64);  // bx/bx+256 pair: sum 127
  const int wq0 = qw * 32;
  const int nt  = (qw >> 1) + 1;     // 64-key tiles covering keys 0..wq0+31

  // Q B-frags (col = l32 = q, k = hl*8+j), resident whole kernel
  short8 qf[4];
  {
    const unsigned short* qp = qfb + (size_t)(b * 128 + qw) * 2048 + lane * 8;
#pragma unroll
    for (int s = 0; s < 4; s++) qf[s] = *(const short8*)(qp + s * 512);
  }

  const unsigned short* kbase = kfb + (size_t)b * 128 * 2048 + lane * 8;
  const unsigned short* vbase = vfb + (size_t)b * 64 * 4096 + lane * 8;

  floatx16 o0, o1;
#pragma unroll
  for (int r = 0; r < 16; r++) { o0[r] = 0.f; o1[r] = 0.f; }
  float ls0 = 0.f, ls1 = 0.f, ls2 = 0.f, ls3 = 0.f;

  // two-stage register double-buffer: loads fly one tile ahead of compute
  short8 ka[8], va[8], kb[8], vb[8];
  int t = wave;
  if (t < nt) ATTN_LOAD(ka, va, t);
  while (t < nt) {
    const int t2 = t + 4;
    if (t2 < nt) ATTN_LOAD(kb, vb, t2);
    ATTN_TILE(ka, va, t * 64);
    t += 8;
    if (t < nt) ATTN_LOAD(ka, va, t);
    if (t2 < nt) ATTN_TILE(kb, vb, t2 * 64);
  }

  // ---- per-wave denominator (q = l32 in both halves) ----
  float lsum = (ls0 + ls1) + (ls2 + ls3);
  lsum += __shfl_xor(lsum, 32);

  // ---- cross-wave reduction in LDS; write FINAL output ----
#pragma unroll
  for (int r = 0; r < 16; r++) {
    const int qr = (r & 3) + 8 * (r >> 2) + 4 * hl;   // q-local 0..31
    Ol[wave][qr][l32]      = o0[r];
    Ol[wave][qr][32 + l32] = o1[r];
  }
  if (hl == 0) Ls[wave][l32] = lsum;
  __syncthreads();

  const int q  = tid >> 3;          // 0..31
  const int dg = (tid & 7) * 8;     // 0..56
  const float L   = Ls[0][q] + Ls[1][q] + Ls[2][q] + Ls[3][q];
  const float inv = 1.0f / L;
  float4 a = {0.f, 0.f, 0.f, 0.f}, c2 = {0.f, 0.f, 0.f, 0.f};
#pragma unroll
  for (int w = 0; w < 4; w++) {
    const float4 pa4 = *(const float4*)&Ol[w][q][dg];
    const float4 pb4 = *(const float4*)&Ol[w][q][dg + 4];
    a.x  += pa4.x; a.y  += pa4.y; a.z  += pa4.z; a.w  += pa4.w;
    c2.x += pb4.x; c2.y += pb4.y; c2.z += pb4.z; c2.w += pb4.w;
  }
  float* op = out + ((size_t)b * SDIM + wq0 + q) * 64 + dg;
  float4 r0v = {a.x * inv, a.y * inv, a.z * inv, a.w * inv};
  float4 r1v = {c2.x * inv, c2.y * inv, c2.z * inv, c2.w * inv};
  *(float4*)op       = r0v;
  *(float4*)(op + 4) = r1v;
}

extern "C" void kernel_launch(void* const* d_in, const int* in_sizes, int n_in,
                              void* d_out, int out_size, void* d_ws, size_t ws_size,
                              hipStream_t stream) {
  const float* x  = (const float*)d_in[0];
  const float* Wq = (const float*)d_in[1];
  const float* Wk = (const float*)d_in[2];
  const float* Wv = (const float*)d_in[3];
  float* out = (float*)d_out;

  // ws layout: q_frag (2MB) | k_frag (2MB) | v_frag (2MB) | wbf (384KB)
  unsigned short* qfb = (unsigned short*)d_ws;
  unsigned short* kfb = qfb + (size_t)1048576;
  unsigned short* vfb = kfb + (size_t)1048576;
  unsigned short* wbf = vfb + (size_t)1048576;

  wcvt_kernel<<<dim3(192), dim3(256), 0, stream>>>(Wq, Wk, Wv, wbf);
  proj_kernel<<<dim3(MTOT / 32), dim3(512), 0, stream>>>(x, wbf, qfb, kfb, vfb);
  attn_kernel<<<dim3(512), dim3(256), 0, stream>>>(qfb, kfb, vfb, out);
}